// Round 12
// baseline (5558.870 us; speedup 1.0000x reference)
//
#include <hip/hip_runtime.h>
#include <hip/hip_fp16.h>

#define N_NODES    100000
#define N_EDGES    1600000
#define D_FEAT     64
#define N_GRAPHS   1000
#define D_MSG      30
#define D_H1       20
#define D_H2       10
#define PROW       32                         // padded row stride (floats) for P0/P1
#define N_SCAN     (N_NODES + 1)
#define N_SCAN_PAD 100004
#define NB_SCAN    ((N_SCAN + 1023) / 1024)   // 98
#define NB_EDGE    (N_EDGES / 256)            // 6250
#define GS         2                          // slots (or nodes) per thread: GS=4 spilled (R10: VGPR=256, 9GB scratch traffic)
#define GTILE      512                        // per-block tile (256 thr * GS)
#define NB_GEMM    ((N_EDGES + GTILE - 1) / GTILE)   // 3125
#define NB_PROJ    ((N_NODES + GTILE - 1) / GTILE)   // 196

// ---------------------------------------------------------------------------
// K0: node projections, register-tiled: thread computes GS nodes x 30 outs.
// grid (NB_PROJ, 2): y=0 -> P0 = x@W0 + b_msg ; y=1 -> P1 = x@W1.
// W-half in LDS (8KB); each broadcast amortized over GS nodes.
// ---------------------------------------------------------------------------
__global__ __launch_bounds__(256) void node_proj_kernel(
    const float* __restrict__ node_attr,   // [N_NODES][64]
    const float* __restrict__ W_msg,       // [192][30]
    const float* __restrict__ b_msg,       // [30]
    float*       __restrict__ P0,          // [N_NODES][PROW]
    float*       __restrict__ P1)          // [N_NODES][PROW]
{
    const int half = blockIdx.y;
    float* __restrict__ Pout = half ? P1 : P0;

    __shared__ float wlds[64 * 32];
    const int t = threadIdx.x;
    {
        const float* Wh = W_msg + half * (D_FEAT * D_MSG);
#pragma unroll
        for (int i = 0; i < 8; ++i) {
            const int f = t + i * 256, k = f >> 5, j = f & 31;
            wlds[f] = (j < D_MSG) ? Wh[k * D_MSG + j] : 0.0f;
        }
    }
    __syncthreads();

    int  nn[GS];
    bool vld[GS];
#pragma unroll
    for (int si = 0; si < GS; ++si) {
        const int n = blockIdx.x * GTILE + si * 256 + t;
        vld[si] = (n < N_NODES);
        nn[si]  = vld[si] ? n : 0;
    }

    float m[GS][32];
#pragma unroll
    for (int si = 0; si < GS; ++si)
#pragma unroll
        for (int j = 0; j < 32; ++j) m[si][j] = 0.0f;

    const float4* na0 = (const float4*)(node_attr + (size_t)nn[0] * D_FEAT);
    const float4* na1 = (const float4*)(node_attr + (size_t)nn[1] * D_FEAT);

#pragma unroll
    for (int kc = 0; kc < 16; ++kc) {
        const float4 v0 = na0[kc];
        const float4 v1 = na1[kc];
        const float e0[4] = { v0.x, v0.y, v0.z, v0.w };
        const float e1[4] = { v1.x, v1.y, v1.z, v1.w };
#pragma unroll
        for (int r = 0; r < 4; ++r) {
            const float4* wr = (const float4*)&wlds[(4 * kc + r) * 32];
#pragma unroll
            for (int jq = 0; jq < 8; ++jq) {
                const float4 wv = wr[jq];
                m[0][4*jq+0] = fmaf(e0[r], wv.x, m[0][4*jq+0]);
                m[0][4*jq+1] = fmaf(e0[r], wv.y, m[0][4*jq+1]);
                m[0][4*jq+2] = fmaf(e0[r], wv.z, m[0][4*jq+2]);
                m[0][4*jq+3] = fmaf(e0[r], wv.w, m[0][4*jq+3]);
                m[1][4*jq+0] = fmaf(e1[r], wv.x, m[1][4*jq+0]);
                m[1][4*jq+1] = fmaf(e1[r], wv.y, m[1][4*jq+1]);
                m[1][4*jq+2] = fmaf(e1[r], wv.z, m[1][4*jq+2]);
                m[1][4*jq+3] = fmaf(e1[r], wv.w, m[1][4*jq+3]);
            }
        }
    }

    if (half == 0) {
#pragma unroll
        for (int si = 0; si < GS; ++si)
#pragma unroll
            for (int j = 0; j < D_MSG; ++j) m[si][j] += b_msg[j];
    }

#pragma unroll
    for (int si = 0; si < GS; ++si) {
        if (!vld[si]) continue;
        m[si][30] = 0.0f; m[si][31] = 0.0f;     // pads must be 0 (gemm reads them)
        float4* pr = (float4*)(Pout + (size_t)nn[si] * PROW);
#pragma unroll
        for (int q = 0; q < 8; ++q)
            pr[q] = make_float4(m[si][4*q], m[si][4*q+1], m[si][4*q+2], m[si][4*q+3]);
    }
}

// ---------------------------------------------------------------------------
// hist + 2-level scan + cursor init (CSR build)
// ---------------------------------------------------------------------------
__global__ __launch_bounds__(256) void hist_kernel(
    const int* __restrict__ edge_index, int* __restrict__ cnt)
{
    const int e = blockIdx.x * 256 + threadIdx.x;
    atomicAdd(&cnt[edge_index[N_EDGES + e]], 1);
}

__global__ __launch_bounds__(1024) void scan_a(
    const int* __restrict__ cnt, int* __restrict__ offs, int* __restrict__ bsum)
{
    __shared__ int sh[1024];
    const int t = threadIdx.x;
    const int i = blockIdx.x * 1024 + t;
    const int v = (i < N_SCAN) ? cnt[i] : 0;
    sh[t] = v;
    __syncthreads();
#pragma unroll
    for (int off = 1; off < 1024; off <<= 1) {
        int u = 0;
        if (t >= off) u = sh[t - off];
        __syncthreads();
        if (t >= off) sh[t] += u;
        __syncthreads();
    }
    if (i < N_SCAN) offs[i] = sh[t] - v;
    if (t == 1023) bsum[blockIdx.x] = sh[1023];
}

__global__ __launch_bounds__(128) void scan_b(int* __restrict__ bsum)
{
    __shared__ int sh[128];
    const int t = threadIdx.x;
    const int v = (t < NB_SCAN) ? bsum[t] : 0;
    sh[t] = v;
    __syncthreads();
#pragma unroll
    for (int off = 1; off < 128; off <<= 1) {
        int u = 0;
        if (t >= off) u = sh[t - off];
        __syncthreads();
        if (t >= off) sh[t] += u;
        __syncthreads();
    }
    if (t < NB_SCAN) bsum[t] = sh[t] - v;
}

__global__ __launch_bounds__(1024) void scan_c(
    int* __restrict__ offs, const int* __restrict__ bsum, int* __restrict__ cur)
{
    const int i = blockIdx.x * 1024 + threadIdx.x;
    if (i < N_SCAN) {
        const int o = offs[i] + bsum[blockIdx.x];
        offs[i] = o;
        cur[i]  = o;
    }
}

// ---------------------------------------------------------------------------
// K4: scatter (edge, src, dst) records into dst-sorted CSR slots. 16B/edge.
// ---------------------------------------------------------------------------
__global__ __launch_bounds__(256) void scatter_rec(
    const int* __restrict__ edge_index, int* __restrict__ cur,
    int4* __restrict__ rec4)
{
    const int e = blockIdx.x * 256 + threadIdx.x;
    const int s = edge_index[e];
    const int d = edge_index[N_EDGES + e];
    const int p = atomicAdd(&cur[d], 1);
    rec4[p] = make_int4(e, s, d, 0);
}

// ---------------------------------------------------------------------------
// K5: msg GEMM, register-tiled: thread computes GS=2 slots x 30 outs.
//   m = P0[src] + P1[dst] + e_attr[e] @ W2 ; relu ; store fp16 slot-major.
// W2 in LDS once/block; each b128 broadcast feeds 8 FMAs (2 slots x 4 comps).
// ---------------------------------------------------------------------------
__global__ __launch_bounds__(256) void msg_gemm_kernel(
    const int4*  __restrict__ rec4,        // [N_EDGES] (e,src,dst)
    const float* __restrict__ P0,          // [N_NODES][PROW]
    const float* __restrict__ P1,          // [N_NODES][PROW]
    const float* __restrict__ edge_attr,   // [N_EDGES][64]
    const float* __restrict__ W_msg,       // rows 128..191 = W2
    unsigned int* __restrict__ msgh)       // [N_EDGES][16] packed fp16 pairs
{
    __shared__ float wlds[64 * 32];
    const int t = threadIdx.x;
    {
        const float* W2 = W_msg + 2 * D_FEAT * D_MSG;
#pragma unroll
        for (int i = 0; i < 8; ++i) {
            const int f = t + i * 256, k = f >> 5, j = f & 31;
            wlds[f] = (j < D_MSG) ? W2[k * D_MSG + j] : 0.0f;
        }
    }
    __syncthreads();

    int  slot[GS];
    bool vld[GS];
    float m[GS][32];

#pragma unroll
    for (int si = 0; si < GS; ++si) {
        const int sl = blockIdx.x * GTILE + si * 256 + t;
        vld[si]  = (sl < N_EDGES);
        slot[si] = vld[si] ? sl : 0;
    }
    const int4 r0 = rec4[slot[0]];
    const int4 r1 = rec4[slot[1]];
    const float4* ep0 = (const float4*)(edge_attr + (size_t)r0.x * D_FEAT);
    const float4* ep1 = (const float4*)(edge_attr + (size_t)r1.x * D_FEAT);

    {
        const float4* a0 = (const float4*)(P0 + (size_t)r0.y * PROW);
        const float4* b0 = (const float4*)(P1 + (size_t)r0.z * PROW);
        const float4* a1 = (const float4*)(P0 + (size_t)r1.y * PROW);
        const float4* b1 = (const float4*)(P1 + (size_t)r1.z * PROW);
#pragma unroll
        for (int q = 0; q < 8; ++q) {
            const float4 x0 = a0[q], y0 = b0[q];
            m[0][4*q+0] = x0.x + y0.x; m[0][4*q+1] = x0.y + y0.y;
            m[0][4*q+2] = x0.z + y0.z; m[0][4*q+3] = x0.w + y0.w;
            const float4 x1 = a1[q], y1 = b1[q];
            m[1][4*q+0] = x1.x + y1.x; m[1][4*q+1] = x1.y + y1.y;
            m[1][4*q+2] = x1.z + y1.z; m[1][4*q+3] = x1.w + y1.w;
        }
    }

#pragma unroll
    for (int kc = 0; kc < 16; ++kc) {
        const float4 v0 = ep0[kc];
        const float4 v1 = ep1[kc];
        const float e0[4] = { v0.x, v0.y, v0.z, v0.w };
        const float e1[4] = { v1.x, v1.y, v1.z, v1.w };
#pragma unroll
        for (int r = 0; r < 4; ++r) {
            const float4* wr = (const float4*)&wlds[(4 * kc + r) * 32];
#pragma unroll
            for (int jq = 0; jq < 8; ++jq) {
                const float4 wv = wr[jq];
                m[0][4*jq+0] = fmaf(e0[r], wv.x, m[0][4*jq+0]);
                m[0][4*jq+1] = fmaf(e0[r], wv.y, m[0][4*jq+1]);
                m[0][4*jq+2] = fmaf(e0[r], wv.z, m[0][4*jq+2]);
                m[0][4*jq+3] = fmaf(e0[r], wv.w, m[0][4*jq+3]);
                m[1][4*jq+0] = fmaf(e1[r], wv.x, m[1][4*jq+0]);
                m[1][4*jq+1] = fmaf(e1[r], wv.y, m[1][4*jq+1]);
                m[1][4*jq+2] = fmaf(e1[r], wv.z, m[1][4*jq+2]);
                m[1][4*jq+3] = fmaf(e1[r], wv.w, m[1][4*jq+3]);
            }
        }
    }

#pragma unroll
    for (int si = 0; si < GS; ++si) {
        if (!vld[si]) continue;
        unsigned int pk[16];
#pragma unroll
        for (int p = 0; p < 15; ++p) {
            const float a = fmaxf(m[si][2*p],   0.0f);
            const float b = fmaxf(m[si][2*p+1], 0.0f);
            const __half2 h2 = __floats2half2_rn(a, b);
            pk[p] = *(const unsigned int*)&h2;
        }
        pk[15] = 0u;
        uint4* orow = (uint4*)(msgh + (size_t)slot[si] * 16);
#pragma unroll
        for (int q = 0; q < 4; ++q)
            orow[q] = make_uint4(pk[4*q], pk[4*q+1], pk[4*q+2], pk[4*q+3]);
    }
}

// ---------------------------------------------------------------------------
// K6: per-node segment sum of fp16 messages + 30->20 head + graph pooling.
// ---------------------------------------------------------------------------
__global__ __launch_bounds__(256) void node_reduce_head(
    const uint4* __restrict__ msgh,     // [N_EDGES][4] (16 packed fp16 pairs)
    const int*   __restrict__ offs,
    const int*   __restrict__ batch,
    const float* __restrict__ W1,       // [30][20]
    const float* __restrict__ b1,       // [20]
    float*       __restrict__ g)        // [N_GRAPHS][20] (pre-zeroed)
{
    const int n = blockIdx.x * 256 + threadIdx.x;
    if (n >= N_NODES) return;

    const int o0 = offs[n], o1 = offs[n + 1];
    float acc[32];
#pragma unroll
    for (int j = 0; j < 32; ++j) acc[j] = 0.0f;

    for (int o = o0; o < o1; ++o) {
        const uint4* row = msgh + (size_t)o * 4;
#pragma unroll
        for (int q = 0; q < 4; ++q) {
            const uint4 u = row[q];
            const unsigned int vv[4] = { u.x, u.y, u.z, u.w };
#pragma unroll
            for (int c = 0; c < 4; ++c) {
                const __half2 h2 = *(const __half2*)&vv[c];
                const float2  f  = __half22float2(h2);
                acc[q*8 + 2*c]     += f.x;
                acc[q*8 + 2*c + 1] += f.y;
            }
        }
    }

    float h[D_H1];
#pragma unroll
    for (int tt = 0; tt < D_H1; ++tt) h[tt] = b1[tt];
#pragma unroll
    for (int j = 0; j < D_MSG; ++j) {
#pragma unroll
        for (int tt = 0; tt < D_H1; ++tt) h[tt] = fmaf(acc[j], W1[j * D_H1 + tt], h[tt]);
    }

    const int gi = batch[n];
    float* gr = g + (size_t)gi * D_H1;
#pragma unroll
    for (int tt = 0; tt < D_H1; ++tt) {
        const float hv = fmaxf(h[tt], 0.0f);
        if (hv > 0.0f) atomicAdd(gr + tt, hv);
    }
}

// ---------------------------------------------------------------------------
// K7: per-graph head  out = relu(g @ W2 + b2) @ W3 + b3
// ---------------------------------------------------------------------------
__global__ __launch_bounds__(256) void graph_head_kernel(
    const float* __restrict__ g, const float* __restrict__ W2,
    const float* __restrict__ b2, const float* __restrict__ W3,
    const float* __restrict__ b3, float* __restrict__ out)
{
    const int i = blockIdx.x * 256 + threadIdx.x;
    if (i >= N_GRAPHS) return;

    float gv[D_H1];
    const float2* pg = (const float2*)(g + (size_t)i * D_H1);
#pragma unroll
    for (int j = 0; j < D_H1 / 2; ++j) {
        const float2 v = pg[j];
        gv[2*j] = v.x; gv[2*j+1] = v.y;
    }

    float h[D_H2];
#pragma unroll
    for (int tt = 0; tt < D_H2; ++tt) h[tt] = b2[tt];
#pragma unroll
    for (int j = 0; j < D_H1; ++j) {
#pragma unroll
        for (int tt = 0; tt < D_H2; ++tt) h[tt] = fmaf(gv[j], W2[j * D_H2 + tt], h[tt]);
    }

    float o = b3[0];
#pragma unroll
    for (int tt = 0; tt < D_H2; ++tt) o = fmaf(fmaxf(h[tt], 0.0f), W3[tt], o);

    out[i] = o;
}

// ---------------------------------------------------------------------------
extern "C" void kernel_launch(void* const* d_in, const int* in_sizes, int n_in,
                              void* d_out, int out_size, void* d_ws, size_t ws_size,
                              hipStream_t stream)
{
    (void)in_sizes; (void)n_in; (void)out_size; (void)ws_size;

    const int*   edge_index = (const int*)  d_in[0];
    const float* node_attr  = (const float*)d_in[1];
    const float* edge_attr  = (const float*)d_in[2];
    const int*   batch      = (const int*)  d_in[3];
    const float* W_msg      = (const float*)d_in[4];
    const float* b_msg      = (const float*)d_in[5];
    const float* W1         = (const float*)d_in[6];
    const float* b1         = (const float*)d_in[7];
    const float* W2         = (const float*)d_in[8];
    const float* b2         = (const float*)d_in[9];
    const float* W3         = (const float*)d_in[10];
    const float* b3         = (const float*)d_in[11];

    // ws: P0[100000*32] | P1[100000*32] | g[20000] | cnt | offs | cur | bsum[128]
    //     | rec4[E int4] | msgh[E*16 u32]     total ~155 MB
    float* P0   = (float*)d_ws;
    float* P1   = P0 + (size_t)N_NODES * PROW;
    float* g    = P1 + (size_t)N_NODES * PROW;
    int*   cnt  = (int*)(g + (size_t)N_GRAPHS * D_H1);
    int*   offs = cnt + N_SCAN_PAD;
    int*   cur  = offs + N_SCAN_PAD;
    int*   bsum = cur + N_SCAN_PAD;
    int4*  rec4 = (int4*)(bsum + 128);
    unsigned int* msgh = (unsigned int*)(rec4 + N_EDGES);

    // zero g + cnt (adjacent)
    (void)hipMemsetAsync(g, 0, ((size_t)N_GRAPHS * D_H1 + N_SCAN_PAD) * 4, stream);

    node_proj_kernel<<<dim3(NB_PROJ, 2), 256, 0, stream>>>(
        node_attr, W_msg, b_msg, P0, P1);

    hist_kernel<<<NB_EDGE, 256, 0, stream>>>(edge_index, cnt);
    scan_a<<<NB_SCAN, 1024, 0, stream>>>(cnt, offs, bsum);
    scan_b<<<1, 128, 0, stream>>>(bsum);
    scan_c<<<NB_SCAN, 1024, 0, stream>>>(offs, bsum, cur);

    scatter_rec<<<NB_EDGE, 256, 0, stream>>>(edge_index, cur, rec4);

    msg_gemm_kernel<<<NB_GEMM, 256, 0, stream>>>(
        rec4, P0, P1, edge_attr, W_msg, msgh);

    node_reduce_head<<<(N_NODES + 255) / 256, 256, 0, stream>>>(
        (const uint4*)msgh, offs, batch, W1, b1, g);

    graph_head_kernel<<<(N_GRAPHS + 255) / 256, 256, 0, stream>>>(
        g, W2, b2, W3, b3, (float*)d_out);
}

// Round 13
// 725.831 us; speedup vs baseline: 7.6586x; 7.6586x over previous
//
#include <hip/hip_runtime.h>
#include <hip/hip_fp16.h>

#define N_NODES    100000
#define N_EDGES    1600000
#define D_FEAT     64
#define N_GRAPHS   1000
#define D_MSG      30
#define D_H1       20
#define D_H2       10
#define PROW       32                         // padded row stride (floats) for P0/P1
#define N_SCAN     (N_NODES + 1)
#define N_SCAN_PAD 100004
#define NB_SCAN    ((N_SCAN + 1023) / 1024)   // 98
#define NB_EDGE    (N_EDGES / 256)            // 6250
#define GS         2                          // slots (or nodes) per thread
#define GTILE      512                        // per-block tile (256 thr * GS)
#define NB_GEMM    ((N_EDGES + GTILE - 1) / GTILE)   // 3125
#define NB_PROJ    ((N_NODES + GTILE - 1) / GTILE)   // 196

// ---------------------------------------------------------------------------
// K0: node projections, register-tiled GS=2. kc loop NOT unrolled: full
// unroll lets the scheduler hoist all global loads -> VGPR blowup + spill
// (R10/R12: VGPR=256, 5-11GB scratch traffic). unroll 1 bounds the window.
// ---------------------------------------------------------------------------
__global__ __launch_bounds__(256) void node_proj_kernel(
    const float* __restrict__ node_attr,   // [N_NODES][64]
    const float* __restrict__ W_msg,       // [192][30]
    const float* __restrict__ b_msg,       // [30]
    float*       __restrict__ P0,          // [N_NODES][PROW]
    float*       __restrict__ P1)          // [N_NODES][PROW]
{
    const int half = blockIdx.y;
    float* __restrict__ Pout = half ? P1 : P0;

    __shared__ float wlds[64 * 32];
    const int t = threadIdx.x;
    {
        const float* Wh = W_msg + half * (D_FEAT * D_MSG);
#pragma unroll
        for (int i = 0; i < 8; ++i) {
            const int f = t + i * 256, k = f >> 5, j = f & 31;
            wlds[f] = (j < D_MSG) ? Wh[k * D_MSG + j] : 0.0f;
        }
    }
    __syncthreads();

    int  nn[GS];
    bool vld[GS];
#pragma unroll
    for (int si = 0; si < GS; ++si) {
        const int n = blockIdx.x * GTILE + si * 256 + t;
        vld[si] = (n < N_NODES);
        nn[si]  = vld[si] ? n : 0;
    }

    float m[GS][32];
#pragma unroll
    for (int si = 0; si < GS; ++si)
#pragma unroll
        for (int j = 0; j < 32; ++j) m[si][j] = 0.0f;

    const float4* na0 = (const float4*)(node_attr + (size_t)nn[0] * D_FEAT);
    const float4* na1 = (const float4*)(node_attr + (size_t)nn[1] * D_FEAT);

#pragma unroll 1
    for (int kc = 0; kc < 16; ++kc) {
        const float4 v0 = na0[kc];
        const float4 v1 = na1[kc];
        const float e0[4] = { v0.x, v0.y, v0.z, v0.w };
        const float e1[4] = { v1.x, v1.y, v1.z, v1.w };
#pragma unroll
        for (int r = 0; r < 4; ++r) {
            const float4* wr = (const float4*)&wlds[(4 * kc + r) * 32];
#pragma unroll
            for (int jq = 0; jq < 8; ++jq) {
                const float4 wv = wr[jq];
                m[0][4*jq+0] = fmaf(e0[r], wv.x, m[0][4*jq+0]);
                m[0][4*jq+1] = fmaf(e0[r], wv.y, m[0][4*jq+1]);
                m[0][4*jq+2] = fmaf(e0[r], wv.z, m[0][4*jq+2]);
                m[0][4*jq+3] = fmaf(e0[r], wv.w, m[0][4*jq+3]);
                m[1][4*jq+0] = fmaf(e1[r], wv.x, m[1][4*jq+0]);
                m[1][4*jq+1] = fmaf(e1[r], wv.y, m[1][4*jq+1]);
                m[1][4*jq+2] = fmaf(e1[r], wv.z, m[1][4*jq+2]);
                m[1][4*jq+3] = fmaf(e1[r], wv.w, m[1][4*jq+3]);
            }
        }
    }

    if (half == 0) {
#pragma unroll
        for (int si = 0; si < GS; ++si)
#pragma unroll
            for (int j = 0; j < D_MSG; ++j) m[si][j] += b_msg[j];
    }

#pragma unroll
    for (int si = 0; si < GS; ++si) {
        if (!vld[si]) continue;
        m[si][30] = 0.0f; m[si][31] = 0.0f;     // pads must be 0 (gemm reads them)
        float4* pr = (float4*)(Pout + (size_t)nn[si] * PROW);
#pragma unroll
        for (int q = 0; q < 8; ++q)
            pr[q] = make_float4(m[si][4*q], m[si][4*q+1], m[si][4*q+2], m[si][4*q+3]);
    }
}

// ---------------------------------------------------------------------------
// hist + 2-level scan + cursor init (CSR build)
// ---------------------------------------------------------------------------
__global__ __launch_bounds__(256) void hist_kernel(
    const int* __restrict__ edge_index, int* __restrict__ cnt)
{
    const int e = blockIdx.x * 256 + threadIdx.x;
    atomicAdd(&cnt[edge_index[N_EDGES + e]], 1);
}

__global__ __launch_bounds__(1024) void scan_a(
    const int* __restrict__ cnt, int* __restrict__ offs, int* __restrict__ bsum)
{
    __shared__ int sh[1024];
    const int t = threadIdx.x;
    const int i = blockIdx.x * 1024 + t;
    const int v = (i < N_SCAN) ? cnt[i] : 0;
    sh[t] = v;
    __syncthreads();
#pragma unroll
    for (int off = 1; off < 1024; off <<= 1) {
        int u = 0;
        if (t >= off) u = sh[t - off];
        __syncthreads();
        if (t >= off) sh[t] += u;
        __syncthreads();
    }
    if (i < N_SCAN) offs[i] = sh[t] - v;
    if (t == 1023) bsum[blockIdx.x] = sh[1023];
}

__global__ __launch_bounds__(128) void scan_b(int* __restrict__ bsum)
{
    __shared__ int sh[128];
    const int t = threadIdx.x;
    const int v = (t < NB_SCAN) ? bsum[t] : 0;
    sh[t] = v;
    __syncthreads();
#pragma unroll
    for (int off = 1; off < 128; off <<= 1) {
        int u = 0;
        if (t >= off) u = sh[t - off];
        __syncthreads();
        if (t >= off) sh[t] += u;
        __syncthreads();
    }
    if (t < NB_SCAN) bsum[t] = sh[t] - v;
}

__global__ __launch_bounds__(1024) void scan_c(
    int* __restrict__ offs, const int* __restrict__ bsum, int* __restrict__ cur)
{
    const int i = blockIdx.x * 1024 + threadIdx.x;
    if (i < N_SCAN) {
        const int o = offs[i] + bsum[blockIdx.x];
        offs[i] = o;
        cur[i]  = o;
    }
}

// ---------------------------------------------------------------------------
// K4: scatter (edge, src, dst) records into dst-sorted CSR slots. 16B/edge.
// ---------------------------------------------------------------------------
__global__ __launch_bounds__(256) void scatter_rec(
    const int* __restrict__ edge_index, int* __restrict__ cur,
    int4* __restrict__ rec4)
{
    const int e = blockIdx.x * 256 + threadIdx.x;
    const int s = edge_index[e];
    const int d = edge_index[N_EDGES + e];
    const int p = atomicAdd(&cur[d], 1);
    rec4[p] = make_int4(e, s, d, 0);
}

// ---------------------------------------------------------------------------
// K5: msg GEMM, register-tiled GS=2 slots x 30 outs, kc loop unroll 1
// (bounded scheduler window -> no spill). W2 in LDS; each b128 broadcast
// feeds 8 FMAs. 4 LDS-instr/edge vs R4's 8 -> LDS-pipe floor ~125us.
// ---------------------------------------------------------------------------
__global__ __launch_bounds__(256) void msg_gemm_kernel(
    const int4*  __restrict__ rec4,        // [N_EDGES] (e,src,dst)
    const float* __restrict__ P0,          // [N_NODES][PROW]
    const float* __restrict__ P1,          // [N_NODES][PROW]
    const float* __restrict__ edge_attr,   // [N_EDGES][64]
    const float* __restrict__ W_msg,       // rows 128..191 = W2
    unsigned int* __restrict__ msgh)       // [N_EDGES][16] packed fp16 pairs
{
    __shared__ float wlds[64 * 32];
    const int t = threadIdx.x;
    {
        const float* W2 = W_msg + 2 * D_FEAT * D_MSG;
#pragma unroll
        for (int i = 0; i < 8; ++i) {
            const int f = t + i * 256, k = f >> 5, j = f & 31;
            wlds[f] = (j < D_MSG) ? W2[k * D_MSG + j] : 0.0f;
        }
    }
    __syncthreads();

    int  slot[GS];
    bool vld[GS];
    float m[GS][32];

#pragma unroll
    for (int si = 0; si < GS; ++si) {
        const int sl = blockIdx.x * GTILE + si * 256 + t;
        vld[si]  = (sl < N_EDGES);
        slot[si] = vld[si] ? sl : 0;
    }
    const int4 r0 = rec4[slot[0]];
    const int4 r1 = rec4[slot[1]];
    const float4* ep0 = (const float4*)(edge_attr + (size_t)r0.x * D_FEAT);
    const float4* ep1 = (const float4*)(edge_attr + (size_t)r1.x * D_FEAT);

    {
        const float4* a0 = (const float4*)(P0 + (size_t)r0.y * PROW);
        const float4* b0 = (const float4*)(P1 + (size_t)r0.z * PROW);
        const float4* a1 = (const float4*)(P0 + (size_t)r1.y * PROW);
        const float4* b1 = (const float4*)(P1 + (size_t)r1.z * PROW);
#pragma unroll
        for (int q = 0; q < 8; ++q) {
            const float4 x0 = a0[q], y0 = b0[q];
            m[0][4*q+0] = x0.x + y0.x; m[0][4*q+1] = x0.y + y0.y;
            m[0][4*q+2] = x0.z + y0.z; m[0][4*q+3] = x0.w + y0.w;
            const float4 x1 = a1[q], y1 = b1[q];
            m[1][4*q+0] = x1.x + y1.x; m[1][4*q+1] = x1.y + y1.y;
            m[1][4*q+2] = x1.z + y1.z; m[1][4*q+3] = x1.w + y1.w;
        }
    }

#pragma unroll 1
    for (int kc = 0; kc < 16; ++kc) {
        const float4 v0 = ep0[kc];
        const float4 v1 = ep1[kc];
        const float e0[4] = { v0.x, v0.y, v0.z, v0.w };
        const float e1[4] = { v1.x, v1.y, v1.z, v1.w };
#pragma unroll
        for (int r = 0; r < 4; ++r) {
            const float4* wr = (const float4*)&wlds[(4 * kc + r) * 32];
#pragma unroll
            for (int jq = 0; jq < 8; ++jq) {
                const float4 wv = wr[jq];
                m[0][4*jq+0] = fmaf(e0[r], wv.x, m[0][4*jq+0]);
                m[0][4*jq+1] = fmaf(e0[r], wv.y, m[0][4*jq+1]);
                m[0][4*jq+2] = fmaf(e0[r], wv.z, m[0][4*jq+2]);
                m[0][4*jq+3] = fmaf(e0[r], wv.w, m[0][4*jq+3]);
                m[1][4*jq+0] = fmaf(e1[r], wv.x, m[1][4*jq+0]);
                m[1][4*jq+1] = fmaf(e1[r], wv.y, m[1][4*jq+1]);
                m[1][4*jq+2] = fmaf(e1[r], wv.z, m[1][4*jq+2]);
                m[1][4*jq+3] = fmaf(e1[r], wv.w, m[1][4*jq+3]);
            }
        }
    }

#pragma unroll
    for (int si = 0; si < GS; ++si) {
        if (!vld[si]) continue;
        unsigned int pk[16];
#pragma unroll
        for (int p = 0; p < 15; ++p) {
            const float a = fmaxf(m[si][2*p],   0.0f);
            const float b = fmaxf(m[si][2*p+1], 0.0f);
            const __half2 h2 = __floats2half2_rn(a, b);
            pk[p] = *(const unsigned int*)&h2;
        }
        pk[15] = 0u;
        uint4* orow = (uint4*)(msgh + (size_t)slot[si] * 16);
#pragma unroll
        for (int q = 0; q < 4; ++q)
            orow[q] = make_uint4(pk[4*q], pk[4*q+1], pk[4*q+2], pk[4*q+3]);
    }
}

// ---------------------------------------------------------------------------
// K6: per-node segment sum of fp16 messages + 30->20 head + graph pooling.
// ---------------------------------------------------------------------------
__global__ __launch_bounds__(256) void node_reduce_head(
    const uint4* __restrict__ msgh,     // [N_EDGES][4] (16 packed fp16 pairs)
    const int*   __restrict__ offs,
    const int*   __restrict__ batch,
    const float* __restrict__ W1,       // [30][20]
    const float* __restrict__ b1,       // [20]
    float*       __restrict__ g)        // [N_GRAPHS][20] (pre-zeroed)
{
    const int n = blockIdx.x * 256 + threadIdx.x;
    if (n >= N_NODES) return;

    const int o0 = offs[n], o1 = offs[n + 1];
    float acc[32];
#pragma unroll
    for (int j = 0; j < 32; ++j) acc[j] = 0.0f;

    for (int o = o0; o < o1; ++o) {
        const uint4* row = msgh + (size_t)o * 4;
#pragma unroll
        for (int q = 0; q < 4; ++q) {
            const uint4 u = row[q];
            const unsigned int vv[4] = { u.x, u.y, u.z, u.w };
#pragma unroll
            for (int c = 0; c < 4; ++c) {
                const __half2 h2 = *(const __half2*)&vv[c];
                const float2  f  = __half22float2(h2);
                acc[q*8 + 2*c]     += f.x;
                acc[q*8 + 2*c + 1] += f.y;
            }
        }
    }

    float h[D_H1];
#pragma unroll
    for (int tt = 0; tt < D_H1; ++tt) h[tt] = b1[tt];
#pragma unroll
    for (int j = 0; j < D_MSG; ++j) {
#pragma unroll
        for (int tt = 0; tt < D_H1; ++tt) h[tt] = fmaf(acc[j], W1[j * D_H1 + tt], h[tt]);
    }

    const int gi = batch[n];
    float* gr = g + (size_t)gi * D_H1;
#pragma unroll
    for (int tt = 0; tt < D_H1; ++tt) {
        const float hv = fmaxf(h[tt], 0.0f);
        if (hv > 0.0f) atomicAdd(gr + tt, hv);
    }
}

// ---------------------------------------------------------------------------
// K7: per-graph head  out = relu(g @ W2 + b2) @ W3 + b3
// ---------------------------------------------------------------------------
__global__ __launch_bounds__(256) void graph_head_kernel(
    const float* __restrict__ g, const float* __restrict__ W2,
    const float* __restrict__ b2, const float* __restrict__ W3,
    const float* __restrict__ b3, float* __restrict__ out)
{
    const int i = blockIdx.x * 256 + threadIdx.x;
    if (i >= N_GRAPHS) return;

    float gv[D_H1];
    const float2* pg = (const float2*)(g + (size_t)i * D_H1);
#pragma unroll
    for (int j = 0; j < D_H1 / 2; ++j) {
        const float2 v = pg[j];
        gv[2*j] = v.x; gv[2*j+1] = v.y;
    }

    float h[D_H2];
#pragma unroll
    for (int tt = 0; tt < D_H2; ++tt) h[tt] = b2[tt];
#pragma unroll
    for (int j = 0; j < D_H1; ++j) {
#pragma unroll
        for (int tt = 0; tt < D_H2; ++tt) h[tt] = fmaf(gv[j], W2[j * D_H2 + tt], h[tt]);
    }

    float o = b3[0];
#pragma unroll
    for (int tt = 0; tt < D_H2; ++tt) o = fmaf(fmaxf(h[tt], 0.0f), W3[tt], o);

    out[i] = o;
}

// ---------------------------------------------------------------------------
extern "C" void kernel_launch(void* const* d_in, const int* in_sizes, int n_in,
                              void* d_out, int out_size, void* d_ws, size_t ws_size,
                              hipStream_t stream)
{
    (void)in_sizes; (void)n_in; (void)out_size; (void)ws_size;

    const int*   edge_index = (const int*)  d_in[0];
    const float* node_attr  = (const float*)d_in[1];
    const float* edge_attr  = (const float*)d_in[2];
    const int*   batch      = (const int*)  d_in[3];
    const float* W_msg      = (const float*)d_in[4];
    const float* b_msg      = (const float*)d_in[5];
    const float* W1         = (const float*)d_in[6];
    const float* b1         = (const float*)d_in[7];
    const float* W2         = (const float*)d_in[8];
    const float* b2         = (const float*)d_in[9];
    const float* W3         = (const float*)d_in[10];
    const float* b3         = (const float*)d_in[11];

    // ws: P0[100000*32] | P1[100000*32] | g[20000] | cnt | offs | cur | bsum[128]
    //     | rec4[E int4] | msgh[E*16 u32]     total ~155 MB
    float* P0   = (float*)d_ws;
    float* P1   = P0 + (size_t)N_NODES * PROW;
    float* g    = P1 + (size_t)N_NODES * PROW;
    int*   cnt  = (int*)(g + (size_t)N_GRAPHS * D_H1);
    int*   offs = cnt + N_SCAN_PAD;
    int*   cur  = offs + N_SCAN_PAD;
    int*   bsum = cur + N_SCAN_PAD;
    int4*  rec4 = (int4*)(bsum + 128);
    unsigned int* msgh = (unsigned int*)(rec4 + N_EDGES);

    // zero g + cnt (adjacent)
    (void)hipMemsetAsync(g, 0, ((size_t)N_GRAPHS * D_H1 + N_SCAN_PAD) * 4, stream);

    node_proj_kernel<<<dim3(NB_PROJ, 2), 256, 0, stream>>>(
        node_attr, W_msg, b_msg, P0, P1);

    hist_kernel<<<NB_EDGE, 256, 0, stream>>>(edge_index, cnt);
    scan_a<<<NB_SCAN, 1024, 0, stream>>>(cnt, offs, bsum);
    scan_b<<<1, 128, 0, stream>>>(bsum);
    scan_c<<<NB_SCAN, 1024, 0, stream>>>(offs, bsum, cur);

    scatter_rec<<<NB_EDGE, 256, 0, stream>>>(edge_index, cur, rec4);

    msg_gemm_kernel<<<NB_GEMM, 256, 0, stream>>>(
        rec4, P0, P1, edge_attr, W_msg, msgh);

    node_reduce_head<<<(N_NODES + 255) / 256, 256, 0, stream>>>(
        (const uint4*)msgh, offs, batch, W1, b1, g);

    graph_head_kernel<<<(N_GRAPHS + 255) / 256, 256, 0, stream>>>(
        g, W2, b2, W3, b3, (float*)d_out);
}